// Round 1
// 913.437 us; speedup vs baseline: 1.0128x; 1.0128x over previous
//
#include <hip/hip_runtime.h>
#include <cstdint>
#include <cstddef>

// Depthwise conv1d (SAME, K=64) + bias + tanh.  B=32, L=32768, C=128.
// out[b][t][c] = tanh( bias[c] + sum_{k=0..63} x[b][t-31+k][c] * w[k][c] )
//
// Strategy: strip-persistent blocks + 64 KiB LDS ring (128 time-rows x 128 ch),
// async global->LDS staging one region/iter, 64 weights in VGPRs, triangular
// statically-unrolled FMA (16 outputs/thread/chunk, 79 LDS reads -> 1024 FMAs).
//
// R1 change vs baseline: replace the per-chunk __syncthreads() (which emits
// s_waitcnt vmcnt(0) lgkmcnt(0) and drains BOTH the in-flight stage loads and
// all 16 output stores every iteration) with counted vmcnt waits + bare
// s_barrier pairs (T3/T4 pattern).  Stores are never waited on; stage loads
// stay in flight across barriers.
//
// vmcnt invariant (per-wave vmem ops per iter, in issue order):
//   [stage: 4 x global_load_lds][compute: none][epilogue: 16 x store_dword]
// Chunk i reads ring regions i,i+1,i+2; newest needed stage is stage(i+2),
// issued at iter i-1.  Ops issued after it: stores(i-1)=16 + stage(i+3)=4
//   -> s_waitcnt vmcnt(20) when this iter issued a stage
//   -> s_waitcnt vmcnt(16) when this iter skipped the stage (tail iters)
// Iters 0..2 need stages 0..4; 0..2 are drained by the prologue
// __syncthreads(); stage(3)@iter0 / stage(4)@iter1 are covered by vmcnt(20)
// (exactly 20 newer ops at their first use).  DO NOT add vmem ops to the loop
// body (incl. register spills) without redoing this count.

#define BQ 32
#define LQ 32768
#define CQ 128
#define KQ 64
#define NSTRIP 16
#define SLEN (LQ / NSTRIP)   // 2048
#define CHUNK 32
#define NCH (SLEN / CHUNK)   // 64
#define RING 128             // ring rows; ring bytes = 128*512 = 65536 exactly
#define RPT 16               // outputs per thread per chunk

typedef const __attribute__((address_space(1))) unsigned int gas1_u32;
typedef __attribute__((address_space(3))) unsigned int las3_u32;

__global__ __launch_bounds__(256, 2) void dwconv_tanh_kernel(
    const float* __restrict__ x, const float* __restrict__ kern,
    const float* __restrict__ bias, float* __restrict__ out) {
  __shared__ __align__(16) float xs[RING * CQ];  // row r at xs[r*128 + c]; 64 KiB

  const int tid = threadIdx.x;
  const int c   = tid & 127;
  const int h   = tid >> 7;                  // 0 or 1: which 16-row half of the chunk
  const int b   = blockIdx.x >> 4;           // / NSTRIP
  const int s   = blockIdx.x & (NSTRIP - 1);
  const int t_s = s * SLEN;
  const bool firstStrip = (s == 0);
  const bool lastStrip  = (s == NSTRIP - 1);

  const float* xb = x + (size_t)b * (LQ * CQ);

  // ---- per-channel weights (64 VGPRs) and bias ----
  float w[KQ];
#pragma unroll
  for (int k = 0; k < KQ; ++k) w[k] = kern[k * CQ + c];
  const float bc = bias[c];

  // ---- async stage of region j: times [t_s - 32 + 32j, +32) -> ring rows (96+32j)&127 .. +31
  auto stage = [&](int j) {
    const int T = t_s - 32 + 32 * j;
    const unsigned slot0 = (96u + 32u * (unsigned)j) & 127u;  // in {0,32,64,96}; no wrap in region
#pragma unroll
    for (int u = 0; u < 4; ++u) {
      const int off  = u * 4096 + tid * 16;  // byte offset within the 16 KiB region
      const int trow = off >> 9;             // 0..31
      const int cb   = off & 511;            // byte within 512 B row (multiple of 16)
      int t = T + trow;
      t = t < 0 ? 0 : (t >= LQ ? LQ - 1 : t);  // clamp: no OOB faults; garbage zero-fixed later
      const float* gp = xb + (size_t)t * CQ + (cb >> 2);
      float* lp = &xs[(slot0 + (unsigned)trow) * CQ + (unsigned)(cb >> 2)];
      __builtin_amdgcn_global_load_lds((gas1_u32*)gp, (las3_u32*)lp, 16, 0, 0);
    }
  };

  // ---- prologue: stage regions 0,1,2 = times [t_s-32, t_s+64) ----
  stage(0); stage(1); stage(2);
  __syncthreads();  // full drain once: regions 0..2 resident
  if (firstStrip) {
    // rows 96..127 hold times t_s-32..t_s-1 (< 0): zero them
#pragma unroll
    for (int u = 0; u < 16; ++u) xs[96 * CQ + u * 256 + tid] = 0.f;
    __syncthreads();
  }

  for (int i = 0; i < NCH; ++i) {
    // prefetch region j=i+3 (needed by chunk i+1); skip j=66, and j=65 on last strip (all t>=L)
    if ((i < NCH - 1) && !(lastStrip && i == NCH - 2)) {
      stage(i + 3);
      // wait for stage(i+2): 20 newer vmem ops allowed (stores(i-1)=16 + this stage=4)
      asm volatile("s_waitcnt vmcnt(20)" ::: "memory");
    } else {
      // no stage issued this iter: only stores(i-1)=16 are newer than stage(i+2)
      asm volatile("s_waitcnt vmcnt(16)" ::: "memory");
    }

    if (lastStrip && i == NCH - 1) {
      // region j=65 (rows 0..31, times >= L): substitute zeros
#pragma unroll
      for (int u = 0; u < 16; ++u) xs[u * 256 + tid] = 0.f;
      asm volatile("s_waitcnt lgkmcnt(0)" ::: "memory");  // publish before barrier
    }

    // pre-compute barrier: all waves' stage(i+2) has landed in LDS
    asm volatile("" ::: "memory");
    __builtin_amdgcn_s_barrier();
    asm volatile("" ::: "memory");

    // ---- compute chunk i: this thread -> outputs t0 .. t0+15 on channel c ----
    const int t0 = t_s + CHUNK * i + RPT * h;
    float acc[RPT];
#pragma unroll
    for (int r = 0; r < RPT; ++r) acc[r] = 0.f;

    // window times [t0-31, t0+47]; ring byte addr = ((t+128)&127)*512 + c*4, wrap via &65535
    const unsigned base = (((unsigned)(t0 + 97) & 127u) << 9) + ((unsigned)c << 2);
    const char* xsb = (const char*)xs;
#pragma unroll
    for (int ii = 0; ii < RPT + KQ - 1; ++ii) {  // 79 reads -> 1024 FMAs
      const unsigned a = (base + (unsigned)(ii * 512)) & 65535u;
      const float v = *(const float*)(xsb + a);
#pragma unroll
      for (int r = 0; r < RPT; ++r) {
        const int k = ii - r;
        if (k >= 0 && k < KQ) acc[r] = fmaf(w[k], v, acc[r]);
      }
    }

    // ---- epilogue: tanh(acc + bias) -> out (coalesced: lanes = consecutive c) ----
    float* op = out + ((size_t)b * LQ + (size_t)t0) * CQ + c;
#pragma unroll
    for (int r = 0; r < RPT; ++r) {
      const float z = acc[r] + bc;
      const float e = __expf(2.0f * z);                       // inf-safe form
      op[(size_t)r * CQ] = 1.0f - 2.0f * __builtin_amdgcn_rcpf(e + 1.0f);
    }

    // post-compute barrier: no wave may issue stage(i+4) (overwrites region i)
    // while another wave still reads region i.  Bare s_barrier: stores and
    // stage loads remain in flight.
    asm volatile("" ::: "memory");
    __builtin_amdgcn_s_barrier();
    asm volatile("" ::: "memory");
  }
}

extern "C" void kernel_launch(void* const* d_in, const int* in_sizes, int n_in,
                              void* d_out, int out_size, void* d_ws, size_t ws_size,
                              hipStream_t stream) {
  const float* x    = (const float*)d_in[0];
  const float* kern = (const float*)d_in[1];
  const float* bias = (const float*)d_in[2];
  float* out        = (float*)d_out;
  dwconv_tanh_kernel<<<dim3(BQ * NSTRIP), dim3(256), 0, stream>>>(x, kern, bias, out);
}

// Round 2
// 887.576 us; speedup vs baseline: 1.0424x; 1.0291x over previous
//
#include <hip/hip_runtime.h>
#include <cstdint>
#include <cstddef>

// Depthwise conv1d (SAME, K=64) + bias + tanh.  B=32, L=32768, C=128.
// out[b][t][c] = tanh( bias[c] + sum_{k=0..63} x[b][t-31+k][c] * w[k][c] )
//
// R2: channel-split blocks (64 ch/block) -> 38 KiB LDS -> 4 blocks/CU
// (16 waves, 4/SIMD, 2x TLP vs R1), and compile-time ds_read offsets via
// 4x-unrolled ring phase + 24-row LDS mirror (no per-read wrap VALU).
//
// LDS layout (38912 B): ring rows 0..127 (row = t mod 128, 256 B/row),
// mirror rows 128..151 duplicating rows 0..23.  Read addr = vb + imm where
// vb = h*2048 + c*4 (h = wave id 0..3, 8-row time shift) and
// imm = ((32*jj + 97 + ii) & 127) * 256 is compile-time (jj = chunk phase
// mod 4).  physical_row = imm_row + 8h <= 151; rows >= 128 hit the mirror,
// which always duplicates the "region == 1 mod 4" slot -- refreshed once per
// 4 chunks (at jj==3) by each wave copying its OWN freshly-staged bytes
// (own-bytes => the per-wave vmcnt wait orders the copy; no extra barrier).
//
// vmcnt invariant (per-wave vmem ops per iter, in issue order):
//   [stage: 2 x global_load_lds][copy: LDS-only][epilogue: 8 x store_dword]
// Chunk i reads ring regions i,i+1,i+2; newest needed stage(i+2) was issued
// at iter i-1.  Ops after it: stores(i-1)=8 + stage(i+3)=2
//   -> s_waitcnt vmcnt(10) when this iter issued a stage
//   -> s_waitcnt vmcnt(8)  when it didn't (tail iters)
// DO NOT add vmem ops to the loop body (incl. register spills) without
// redoing this count.  __launch_bounds__(256,4) caps VGPR at 128 for
// 4 blocks/CU; if the compiler spills, correctness breaks visibly.

#define BQ 32
#define LQ 32768
#define CQ 128               // global channels
#define BC 64                // channels per block
#define KQ 64
#define NSTRIP 16
#define SLEN (LQ / NSTRIP)   // 2048
#define CHUNK 32
#define NCH (SLEN / CHUNK)   // 64
#define RINGB 32768          // 128 rows * 256 B
#define MIRB 6144            // 24 mirror rows * 256 B
#define RPT 8                // outputs per thread per chunk

typedef const __attribute__((address_space(1))) unsigned int gas1_u32;
typedef __attribute__((address_space(3))) unsigned int las3_u32;

__global__ __launch_bounds__(256, 4) void dwconv_tanh_kernel(
    const float* __restrict__ x, const float* __restrict__ kern,
    const float* __restrict__ bias, float* __restrict__ out) {
  __shared__ __align__(16) float xs[(RINGB + MIRB) / 4];  // 38912 B

  const int tid = threadIdx.x;
  const int c   = tid & (BC - 1);
  const int h   = tid >> 6;                  // wave id 0..3: 8-row time shift
  const int bid = blockIdx.x;
  const int cg  = bid & 1;                   // channel group (0: ch 0..63, 1: 64..127)
  const int s   = (bid >> 1) & (NSTRIP - 1);
  const int b   = bid >> 5;
  const int t_s = s * SLEN;
  const bool firstStrip = (s == 0);
  const bool lastStrip  = (s == NSTRIP - 1);

  const float* xb = x + (size_t)b * (LQ * CQ) + cg * BC;

  // ---- per-channel weights (64 VGPRs) and bias ----
  float w[KQ];
#pragma unroll
  for (int k = 0; k < KQ; ++k) w[k] = kern[k * CQ + cg * BC + c];
  const float bc = bias[cg * BC + c];

  // ---- async stage of region j: times [t_s-32+32j, +32) -> ring rows (96+32j)&127 ..+31
  // srowbyte = ((96+32j)&127)*256, passed compile-time.  LDS dest is linear
  // (wave-uniform base + lane*16) as global_load_lds requires.
  auto stage = [&](int j, int srowbyte) {
#pragma unroll
    for (int u = 0; u < 2; ++u) {
      const int off  = u * 4096 + tid * 16;   // byte offset in the 8 KiB region
      const int trow = off >> 8;              // 0..31
      const int cb   = off & 255;             // byte within 256 B row
      int t = t_s - 32 + 32 * j + trow;
      t = t < 0 ? 0 : (t >= LQ ? LQ - 1 : t); // clamp: no OOB; garbage zero-fixed
      const float* gp = xb + (size_t)t * CQ + (cb >> 2);
      float* lp = (float*)((char*)xs + srowbyte + off);
      __builtin_amdgcn_global_load_lds((gas1_u32*)gp, (las3_u32*)lp, 16, 0, 0);
    }
  };

  // ---- prologue: regions 0,1,2; zero-fix region 0 on first strip; seed mirror
  stage(0, 24576); stage(1, 0); stage(2, 8192);
  __syncthreads();  // full drain once: regions 0..2 resident
  const int o0 = tid * 16;
  if (firstStrip) {
    const float4 z4 = {0.f, 0.f, 0.f, 0.f};
    *(float4*)((char*)xs + 24576 + o0) = z4;   // rows 96..111
    *(float4*)((char*)xs + 28672 + o0) = z4;   // rows 112..127
  }
  {  // mirror <- rows 0..23 (region 1)
    float4 a0 = *(const float4*)((const char*)xs + o0);
    *(float4*)((char*)xs + RINGB + o0) = a0;
    if (tid < 128) {
      float4 a1 = *(const float4*)((const char*)xs + 4096 + o0);
      *(float4*)((char*)xs + RINGB + 4096 + o0) = a1;
    }
  }
  __syncthreads();

  for (int io = 0; io < NCH / 4; ++io) {
#pragma unroll
    for (int jj = 0; jj < 4; ++jj) {
      const int i = io * 4 + jj;
      const int slotb = ((64 + 32 * jj) & 127) * 256;  // stage(i+3) slot, compile-time
      const bool doStage = (i < NCH - 1) && !(lastStrip && i == NCH - 2);
      if (doStage) {
        stage(i + 3, slotb);
        asm volatile("s_waitcnt vmcnt(10)" ::: "memory");
      } else {
        asm volatile("s_waitcnt vmcnt(8)" ::: "memory");
      }

      if (jj == 3) {
        if (lastStrip && i == NCH - 1) {
          // region 65 (rows 0..31, times >= L) + its mirror: zeros
          const float4 z4 = {0.f, 0.f, 0.f, 0.f};
          *(float4*)((char*)xs + o0) = z4;
          *(float4*)((char*)xs + 4096 + o0) = z4;
          *(float4*)((char*)xs + RINGB + o0) = z4;
          if (tid < 128) *(float4*)((char*)xs + RINGB + 4096 + o0) = z4;
        } else {
          // mirror <- rows 0..23 of the region staged at jj==2 (landed per vmcnt
          // above; each wave copies only bytes ITS OWN stage loads wrote).
          float4 a0 = *(const float4*)((const char*)xs + o0);
          *(float4*)((char*)xs + RINGB + o0) = a0;
          if (tid < 128) {
            float4 a1 = *(const float4*)((const char*)xs + 4096 + o0);
            *(float4*)((char*)xs + RINGB + 4096 + o0) = a1;
          }
        }
        asm volatile("s_waitcnt lgkmcnt(0)" ::: "memory");  // publish before barrier
      }

      // pre-compute barrier: all waves' stage(i+2) (and mirror) visible
      asm volatile("" ::: "memory");
      __builtin_amdgcn_s_barrier();
      asm volatile("" ::: "memory");

      // ---- compute chunk i: outputs t0..t0+7 on channel cg*64+c ----
      const int t0 = t_s + CHUNK * i + RPT * h;
      float acc[RPT];
#pragma unroll
      for (int r = 0; r < RPT; ++r) acc[r] = 0.f;

      const char* xsb = (const char*)xs;
      const unsigned vb = ((unsigned)h << 11) + ((unsigned)c << 2);  // h*2048 + c*4
#pragma unroll
      for (int ii = 0; ii < RPT + KQ - 1; ++ii) {  // 71 reads -> 512 FMAs
        const int imm = ((32 * jj + 97 + ii) & 127) * 256;  // compile-time offset
        const float v = *(const float*)(xsb + vb + imm);
#pragma unroll
        for (int r = 0; r < RPT; ++r) {
          const int k = ii - r;
          if (k >= 0 && k < KQ) acc[r] = fmaf(w[k], v, acc[r]);
        }
      }

      // ---- epilogue: tanh(acc + bias) -> out (lanes = consecutive c) ----
      float* op = out + ((size_t)b * LQ + (size_t)t0) * CQ + cg * BC + c;
#pragma unroll
      for (int r = 0; r < RPT; ++r) {
        const float z = acc[r] + bc;
        const float e = __expf(2.0f * z);
        op[(size_t)r * CQ] = 1.0f - 2.0f * __builtin_amdgcn_rcpf(e + 1.0f);
      }

      // post-compute barrier: nobody stages over region i while it's read
      asm volatile("" ::: "memory");
      __builtin_amdgcn_s_barrier();
      asm volatile("" ::: "memory");
    }
  }
}

extern "C" void kernel_launch(void* const* d_in, const int* in_sizes, int n_in,
                              void* d_out, int out_size, void* d_ws, size_t ws_size,
                              hipStream_t stream) {
  const float* x    = (const float*)d_in[0];
  const float* kern = (const float*)d_in[1];
  const float* bias = (const float*)d_in[2];
  float* out        = (float*)d_out;
  dwconv_tanh_kernel<<<dim3(BQ * NSTRIP * 2), dim3(256), 0, stream>>>(x, kern, bias, out);
}